// Round 11
// baseline (292.142 us; speedup 1.0000x reference)
//
#include <hip/hip_runtime.h>
#include <hip/hip_bf16.h>

#define T_TOK 2048
#define HID   1024
#define EXP   64
#define TOPK  8
#define IMED  512
#define N1 (EXP * IMED)   // 32768
#define C1 (N1 / 8)       // 4096
#define N2 (EXP * HID)    // 65536
#define C2 (N2 / 8)       // 8192
#define MAXTILES 320      // >= sum ceil(n_e/64) worst case (256 + 64)

typedef _Float16 h16x2 __attribute__((ext_vector_type(2)));
typedef _Float16 h16x8 __attribute__((ext_vector_type(8)));
typedef float f32x4 __attribute__((ext_vector_type(4)));
typedef unsigned short ushortx4 __attribute__((ext_vector_type(4)));
typedef unsigned short ushortx8 __attribute__((ext_vector_type(8)));

__constant__ int kShifts[8] = {0, 16, 4, 20, 8, 24, 12, 28};

__device__ __forceinline__ void async16(const void* g, void* l) {
  __builtin_amdgcn_global_load_lds((const __attribute__((address_space(1))) void*)g,
                                   (__attribute__((address_space(3))) void*)l, 16, 0, 0);
}

__device__ __forceinline__ unsigned short f2h(float f) {
  return __builtin_bit_cast(unsigned short, (_Float16)f);
}
__device__ __forceinline__ float h2f(unsigned short b) {
  return (float)__builtin_bit_cast(_Float16, b);
}

// magic fp16 dequant: nibble|0x6400 = fp16(1024+q); (1024+q)-(1024+z) exact; *s.
__device__ __forceinline__ h16x8 unpack8h(unsigned q, h16x2 sh2, h16x2 zh2) {
  union { unsigned u[4]; h16x8 v; } out;
#pragma unroll
  for (int j = 0; j < 4; ++j) {
    const unsigned m = ((q >> (4 * j)) & 0x000F000Fu) | 0x64006400u;
    h16x2 d = __builtin_bit_cast(h16x2, m) - zh2;
    d = d * sh2;
    out.u[j] = __builtin_bit_cast(unsigned, d);
  }
  return out.v;
}

// ---------------- Repack body (verified R6/R9): AWQ nibbles -> qk[nblk][t][fq][fr][2] ----------------
__device__ __forceinline__ void repack_body(const int* __restrict__ qw,
                                            unsigned* __restrict__ qk, int K, int C,
                                            int gx, int pp, int tid) {
  const int t = pp >> 2, fq = pp & 3;
  const int c2 = gx * 512 + tid * 2;  // even qw dword-col
  const int nblk = c2 >> 1;
  unsigned o0[16], o1[16];
#pragma unroll
  for (int i = 0; i < 16; ++i) { o0[i] = 0u; o1[i] = 0u; }
  const int k0a = t * 64 + fq * 8;
  const int k0b = t * 64 + (fq + 4) * 8;
#pragma unroll
  for (int r = 0; r < 8; ++r) {
    const int2 va = *reinterpret_cast<const int2*>(qw + (size_t)(k0a + r) * C + c2);
    const int2 vb = *reinterpret_cast<const int2*>(qw + (size_t)(k0b + r) * C + c2);
    const int outsh = (r & 1) * 16 + (r >> 1) * 4;
    const unsigned qa[2] = {(unsigned)va.x, (unsigned)va.y};
    const unsigned qb[2] = {(unsigned)vb.x, (unsigned)vb.y};
#pragma unroll
    for (int ci = 0; ci < 2; ++ci) {
#pragma unroll
      for (int j = 0; j < 8; ++j) {
        const int sh = kShifts[j];
        o0[ci * 8 + j] |= ((qa[ci] >> sh) & 0xFu) << outsh;
        o1[ci * 8 + j] |= ((qb[ci] >> sh) & 0xFu) << outsh;
      }
    }
  }
  unsigned* dst = qk + (size_t)nblk * 2 * K + t * 128 + fq * 32;
#pragma unroll
  for (int idx = 0; idx < 16; ++idx)
    *reinterpret_cast<uint2*>(dst + idx * 2) = make_uint2(o0[idx], o1[idx]);
}

// ---------------- Prep: one launch = {cast+logits f32 16-split (R9 verified)} U repack1 U repack2 ----------------
// bid 0..511: logits tile (32 t-tiles x 16 k-splits of 64), writes xh during staging.
// bid 512..1023: repack1.  bid 1024..1535: repack2 (block 1535 also zeros counts/done_ctr).
__global__ __launch_bounds__(256) void prep_kernel(
    const float* __restrict__ x, const float* __restrict__ gate_w,
    unsigned short* __restrict__ xh, float* __restrict__ partial,
    const int* __restrict__ qw1, unsigned* __restrict__ qk1,
    const int* __restrict__ qw2, unsigned* __restrict__ qk2,
    int* __restrict__ counts, int* __restrict__ done_ctr) {
  const int bid = blockIdx.x;
  const int tid = threadIdx.x;
  if (bid == 1535) {
    if (tid < 64) counts[tid] = 0;
    if (tid == 64) *done_ctr = 0;
  }
  if (bid < 512) {
    __shared__ float xs[64][64];
    __shared__ float gs[64][64];
    const int t0 = (bid & 31) * 64;
    const int ks = bid >> 5;   // 0..15
    const int k0 = ks * 64;
    const int lrow = tid >> 4;        // 0..15
    const int cblk = tid & 15;        // float4 block
#pragma unroll
    for (int r = 0; r < 4; ++r) {
      const int row = r * 16 + lrow;
      const int sc = (cblk ^ ((row >> 2) & 15)) * 4;  // XOR swizzle (16 f4-blocks/row)
      float4 xv = *reinterpret_cast<const float4*>(x + (size_t)(t0 + row) * HID + k0 + cblk * 4);
      float4 gv = *reinterpret_cast<const float4*>(gate_w + (size_t)row * HID + k0 + cblk * 4);
      *reinterpret_cast<float4*>(&xs[row][sc]) = xv;
      *reinterpret_cast<float4*>(&gs[row][sc]) = gv;
      ushortx4 o;
      o[0] = f2h(xv.x); o[1] = f2h(xv.y); o[2] = f2h(xv.z); o[3] = f2h(xv.w);
      *reinterpret_cast<ushortx4*>(xh + (size_t)(t0 + row) * HID + k0 + cblk * 4) = o;
    }
    __syncthreads();
    const int tg = (tid >> 4) * 4, eg = (tid & 15) * 4;
    const int xsw = tid >> 4, gsw = tid & 15;
    float acc[4][4] = {{0.f, 0.f, 0.f, 0.f}};
#pragma unroll 4
    for (int c = 0; c < 16; ++c) {
      float4 a[4], b[4];
#pragma unroll
      for (int i = 0; i < 4; ++i)
        a[i] = *reinterpret_cast<const float4*>(&xs[tg + i][(c ^ xsw) * 4]);
#pragma unroll
      for (int j = 0; j < 4; ++j)
        b[j] = *reinterpret_cast<const float4*>(&gs[eg + j][(c ^ gsw) * 4]);
#pragma unroll
      for (int i = 0; i < 4; ++i)
#pragma unroll
        for (int j = 0; j < 4; ++j) {
          acc[i][j] = fmaf(a[i].x, b[j].x, acc[i][j]);
          acc[i][j] = fmaf(a[i].y, b[j].y, acc[i][j]);
          acc[i][j] = fmaf(a[i].z, b[j].z, acc[i][j]);
          acc[i][j] = fmaf(a[i].w, b[j].w, acc[i][j]);
        }
    }
    float* dst = partial + ((size_t)ks * T_TOK + t0) * EXP;
#pragma unroll
    for (int i = 0; i < 4; ++i)
      *reinterpret_cast<float4*>(dst + (tg + i) * EXP + eg) =
          make_float4(acc[i][0], acc[i][1], acc[i][2], acc[i][3]);
  } else if (bid < 1024) {
    const int id = bid - 512;
    repack_body(qw1, qk1, HID, C1, id & 7, id >> 3, tid);
  } else {
    const int id = bid - 1024;
    repack_body(qw2, qk2, IMED, C2, id & 15, id >> 4, tid);
  }
}

// ---------------- Top-k (R10 verified, 16-split fold) + fused last-block tile build ----------------
__global__ __launch_bounds__(256) void topk_kernel(
    const float* __restrict__ partial, int* __restrict__ counts,
    int* __restrict__ tok_list, int* __restrict__ hslot_list,
    float* __restrict__ cw_list, int2* __restrict__ tiles,
    int* __restrict__ tile_cnt, int* __restrict__ done_ctr) {
  const int wave = threadIdx.x >> 6, lane = threadIdx.x & 63;
  const int t = blockIdx.x * 4 + wave;
  float lg = 0.f;
#pragma unroll
  for (int s = 0; s < 16; ++s)
    lg += partial[((size_t)s * T_TOK + t) * EXP + lane];

  float m = lg;
  for (int off = 32; off; off >>= 1) m = fmaxf(m, __shfl_xor(m, off));
  float pe = expf(lg - m);
  float s = pe;
  for (int off = 32; off; off >>= 1) s += __shfl_xor(s, off);
  float prob = pe / s;

  float pcur = prob;
  float myv = 0.f;
  int myi = -1;
  float tsum = 0.f;
  for (int k = 0; k < TOPK; ++k) {
    float vv = pcur;
    int idx = lane;
    for (int off = 32; off; off >>= 1) {
      float ov = __shfl_xor(vv, off);
      int oi = __shfl_xor(idx, off);
      if (ov > vv || (ov == vv && oi < idx)) { vv = ov; idx = oi; }
    }
    tsum += vv;
    if (lane == k) { myv = vv; myi = idx; }
    if (lane == idx) pcur = -1.f;
  }

  if (lane < TOPK) {
    const float cw = myv / tsum;
    const int ex = myi;
    const int slot = atomicAdd(&counts[ex], 1);
    tok_list[ex * T_TOK + slot] = t;
    hslot_list[ex * T_TOK + slot] = t * TOPK + lane;
    cw_list[ex * T_TOK + slot] = cw;
  }

  // last block to finish builds the dense tile list (counts read via device-scope atomic)
  __threadfence();
  __syncthreads();
  __shared__ int ticket;
  if (threadIdx.x == 0) ticket = atomicAdd(done_ctr, 1);
  __syncthreads();
  if (ticket == (int)gridDim.x - 1 && threadIdx.x < 64) {
    const int ln = threadIdx.x;
    const int n = atomicAdd(&counts[ln], 0);  // coherent read
    const int nt = (n + 63) >> 6;
    int off = nt;
    for (int d = 1; d < 64; d <<= 1) {
      const int v = __shfl_up(off, d);
      if (ln >= d) off += v;
    }
    const int excl = off - nt;
    for (int i = 0; i < nt; ++i) tiles[excl + i] = make_int2(ln, i * 64);
    if (ln == 63) *tile_cnt = excl + nt;
  }
}

// ---------------- MFMA GEMM1: M64xN64, waves 1x4, BK=64, fp16 magic dequant (R10 body, verified) ----------------
__global__ __launch_bounds__(256) void mfma_gemm1(
    const unsigned short* __restrict__ xh, const unsigned* __restrict__ qk1,
    const int* __restrict__ qz1, const float* __restrict__ sc1,
    const int* __restrict__ counts, const int2* __restrict__ tiles,
    const int* __restrict__ tile_cnt, const int* __restrict__ tok_list,
    const int* __restrict__ hslot_list, const float* __restrict__ cw_list,
    unsigned short* __restrict__ h_buf) {
  if ((int)blockIdx.y >= *tile_cnt) return;
  const int2 te = tiles[blockIdx.y];
  const int e = te.x;
  const int t0 = te.y;
  const int n_e = counts[e];
  const int ntile = blockIdx.x;  // 0..7
  const int tid = threadIdx.x;
  const int wave = tid >> 6, lane = tid & 63;
  const int fr = lane & 15, fq = lane >> 4;

  __shared__ unsigned short As[2][64 * 64];  // 2 x 8KB, XOR-swizzled source (verified R4)

  const int arow = tid >> 3;                            // 0..31
  const int acb = ((tid & 7) ^ ((tid >> 3) & 7)) * 16;  // pre-swizzled byte col
  const int ta0 = tok_list[e * T_TOK + min(t0 + arow, n_e - 1)];
  const int ta1 = tok_list[e * T_TOK + min(t0 + 32 + arow, n_e - 1)];
  const char* ga0 = (const char*)(xh + (size_t)ta0 * HID) + acb;
  const char* ga1 = (const char*)(xh + (size_t)ta1 * HID) + acb;

  auto stage = [&](int b) {
    char* l = (char*)&As[b][0] + wave * 1024;  // + HW lane*16
    async16(ga0, l);
    async16(ga1, l + 4096);
    ga0 += 128; ga1 += 128;
  };

  // B: qk1[nblk][t][fq][fr][2]; wave owns 16 cols, lane col = nbase + fr
  const int nbase = e * IMED + ntile * 64 + wave * 16;
  const unsigned* bp = qk1 + (size_t)(nbase >> 4) * (2 * HID) + fq * 32 + fr * 2;
  const int col = nbase + fr;
  const int shz = ((fr >> 1) & 3) * 4 + (fr & 1) * 16;  // kShifts[fr&7]

  f32x4 acc[4];
#pragma unroll
  for (int i = 0; i < 4; ++i) acc[i] = (f32x4){0.f, 0.f, 0.f, 0.f};

  stage(0);
  uint2 qcur = *reinterpret_cast<const uint2*>(bp);
  float s_cur = sc1[col];
  unsigned zd_cur = (unsigned)qz1[col >> 3];
  int p = 0;
#pragma unroll 1
  for (int g = 0; g < HID / 128; ++g) {
    const unsigned shb = (unsigned)f2h(s_cur);
    const h16x2 sh2 = __builtin_bit_cast(h16x2, shb | (shb << 16));
    const unsigned zb = 0x6400u | ((zd_cur >> shz) & 15u);
    const h16x2 zh2 = __builtin_bit_cast(h16x2, zb | (zb << 16));
    float s_nxt = 0.f; unsigned zd_nxt = 0u;
#pragma unroll
    for (int hh = 0; hh < 2; ++hh) {
      const int t = g * 2 + hh;
      __syncthreads();  // As[p] ready
      if (t + 1 < HID / 64) stage(p ^ 1);
      uint2 qnext = make_uint2(0u, 0u);
      if (t + 1 < HID / 64) qnext = *reinterpret_cast<const uint2*>(bp + (t + 1) * 128);
      if (hh == 1 && g + 1 < HID / 128) {
        s_nxt = sc1[(size_t)(g + 1) * N1 + col];
        zd_nxt = (unsigned)qz1[(size_t)(g + 1) * C1 + (col >> 3)];
      }
      const h16x8 b0 = unpack8h(qcur.x, sh2, zh2);
      const h16x8 b1 = unpack8h(qcur.y, sh2, zh2);
#pragma unroll
      for (int kk = 0; kk < 2; ++kk) {
        const h16x8 bb = kk ? b1 : b0;
#pragma unroll
        for (int i = 0; i < 4; ++i) {
          const int row = i * 16 + fr;
          const h16x8 a = *reinterpret_cast<const h16x8*>(
              &As[p][row * 64 + (((kk * 4 + fq) ^ (fr & 7)) * 8)]);
          acc[i] = __builtin_amdgcn_mfma_f32_16x16x32_f16(a, bb, acc[i], 0, 0, 0);
        }
      }
      qcur = qnext; p ^= 1;
    }
    s_cur = s_nxt; zd_cur = zd_nxt;
  }

  // epilogue: C/D map col = lane&15, row = (lane>>4)*4 + reg
#pragma unroll
  for (int i = 0; i < 4; ++i) {
#pragma unroll
    for (int r = 0; r < 4; ++r) {
      const int grow = t0 + i * 16 + fq * 4 + r;
      if (grow < n_e) {
        const float cw = cw_list[e * T_TOK + grow];
        const int hs = hslot_list[e * T_TOK + grow];
        const float v = acc[i][r];
        h_buf[(size_t)hs * IMED + ntile * 64 + wave * 16 + fr] =
            f2h((v / (1.f + expf(-v))) * cw);
      }
    }
  }
}

// ---------------- MFMA GEMM2: M64xN64, waves 1x4, BK=64, fp16 magic dequant (R10 body, verified) ----------------
__global__ __launch_bounds__(256) void mfma_gemm2(
    const unsigned short* __restrict__ h_buf, const unsigned* __restrict__ qk2,
    const int* __restrict__ qz2, const float* __restrict__ sc2,
    const int* __restrict__ counts, const int2* __restrict__ tiles,
    const int* __restrict__ tile_cnt, const int* __restrict__ hslot_list,
    unsigned short* __restrict__ p_buf) {
  if ((int)blockIdx.y >= *tile_cnt) return;
  const int2 te = tiles[blockIdx.y];
  const int e = te.x;
  const int t0 = te.y;
  const int n_e = counts[e];
  const int ntile = blockIdx.x;  // 0..15
  const int tid = threadIdx.x;
  const int wave = tid >> 6, lane = tid & 63;
  const int fr = lane & 15, fq = lane >> 4;

  __shared__ unsigned short As[2][64 * 64];

  const int arow = tid >> 3;
  const int acb = ((tid & 7) ^ ((tid >> 3) & 7)) * 16;
  const int ha0 = hslot_list[e * T_TOK + min(t0 + arow, n_e - 1)];
  const int ha1 = hslot_list[e * T_TOK + min(t0 + 32 + arow, n_e - 1)];
  const char* ga0 = (const char*)(h_buf + (size_t)ha0 * IMED) + acb;
  const char* ga1 = (const char*)(h_buf + (size_t)ha1 * IMED) + acb;

  auto stage = [&](int b) {
    char* l = (char*)&As[b][0] + wave * 1024;
    async16(ga0, l);
    async16(ga1, l + 4096);
    ga0 += 128; ga1 += 128;
  };

  const int nbase = e * HID + ntile * 64 + wave * 16;
  const unsigned* bp = qk2 + (size_t)(nbase >> 4) * (2 * IMED) + fq * 32 + fr * 2;
  const int col = nbase + fr;
  const int shz = ((fr >> 1) & 3) * 4 + (fr & 1) * 16;

  f32x4 acc[4];
#pragma unroll
  for (int i = 0; i < 4; ++i) acc[i] = (f32x4){0.f, 0.f, 0.f, 0.f};

  stage(0);
  uint2 qcur = *reinterpret_cast<const uint2*>(bp);
  float s_cur = sc2[col];
  unsigned zd_cur = (unsigned)qz2[col >> 3];
  int p = 0;
#pragma unroll 1
  for (int g = 0; g < IMED / 128; ++g) {
    const unsigned shb = (unsigned)f2h(s_cur);
    const h16x2 sh2 = __builtin_bit_cast(h16x2, shb | (shb << 16));
    const unsigned zb = 0x6400u | ((zd_cur >> shz) & 15u);
    const h16x2 zh2 = __builtin_bit_cast(h16x2, zb | (zb << 16));
    float s_nxt = 0.f; unsigned zd_nxt = 0u;
#pragma unroll
    for (int hh = 0; hh < 2; ++hh) {
      const int t = g * 2 + hh;
      __syncthreads();
      if (t + 1 < IMED / 64) stage(p ^ 1);
      uint2 qnext = make_uint2(0u, 0u);
      if (t + 1 < IMED / 64) qnext = *reinterpret_cast<const uint2*>(bp + (t + 1) * 128);
      if (hh == 1 && g + 1 < IMED / 128) {
        s_nxt = sc2[(size_t)(g + 1) * N2 + col];
        zd_nxt = (unsigned)qz2[(size_t)(g + 1) * C2 + (col >> 3)];
      }
      const h16x8 b0 = unpack8h(qcur.x, sh2, zh2);
      const h16x8 b1 = unpack8h(qcur.y, sh2, zh2);
#pragma unroll
      for (int kk = 0; kk < 2; ++kk) {
        const h16x8 bb = kk ? b1 : b0;
#pragma unroll
        for (int i = 0; i < 4; ++i) {
          const int row = i * 16 + fr;
          const h16x8 a = *reinterpret_cast<const h16x8*>(
              &As[p][row * 64 + (((kk * 4 + fq) ^ (fr & 7)) * 8)]);
          acc[i] = __builtin_amdgcn_mfma_f32_16x16x32_f16(a, bb, acc[i], 0, 0, 0);
        }
      }
      qcur = qnext; p ^= 1;
    }
    s_cur = s_nxt; zd_cur = zd_nxt;
  }

  // epilogue: plain fp16 partial stores; every (hslot, col) written once
#pragma unroll
  for (int i = 0; i < 4; ++i) {
#pragma unroll
    for (int r = 0; r < 4; ++r) {
      const int grow = t0 + i * 16 + fq * 4 + r;
      if (grow < n_e) {
        const int hs = hslot_list[e * T_TOK + grow];
        p_buf[(size_t)hs * HID + ntile * 64 + wave * 16 + fr] = f2h(acc[i][r]);
      }
    }
  }
}

// ---------------- Reduce 8 partials per token -> out (fp32, verified R8) ----------------
__global__ __launch_bounds__(256) void reduce_kernel(const unsigned short* __restrict__ p_buf,
                                                     float* __restrict__ out) {
  const int idx = blockIdx.x * 256 + threadIdx.x;
  const int t = idx >> 7;
  const int c0 = (idx & 127) * 8;
  float s[8] = {0.f, 0.f, 0.f, 0.f, 0.f, 0.f, 0.f, 0.f};
#pragma unroll
  for (int k = 0; k < TOPK; ++k) {
    ushortx8 v = *reinterpret_cast<const ushortx8*>(p_buf + ((size_t)t * TOPK + k) * HID + c0);
#pragma unroll
    for (int j = 0; j < 8; ++j) s[j] += h2f(v[j]);
  }
  float* dst = out + (size_t)t * HID + c0;
  *reinterpret_cast<float4*>(dst) = make_float4(s[0], s[1], s[2], s[3]);
  *reinterpret_cast<float4*>(dst + 4) = make_float4(s[4], s[5], s[6], s[7]);
}

extern "C" void kernel_launch(void* const* d_in, const int* in_sizes, int n_in,
                              void* d_out, int out_size, void* d_ws, size_t ws_size,
                              hipStream_t stream) {
  const float* x      = (const float*)d_in[0];
  const float* gate_w = (const float*)d_in[1];
  const int*   qw1    = (const int*)d_in[2];
  const int*   qz1    = (const int*)d_in[3];
  const float* sc1    = (const float*)d_in[4];
  const int*   qw2    = (const int*)d_in[5];
  const int*   qz2    = (const int*)d_in[6];
  const float* sc2    = (const float*)d_in[7];
  float* out = (float*)d_out;

  // workspace layout
  char* ws = (char*)d_ws;
  int* counts           = (int*)(ws);                        // 256 B
  int* tok_list         = (int*)(ws + 256);                  // 512 KB
  int* hslot_list       = (int*)(ws + 524544);               // 512 KB
  float* cw_list        = (float*)(ws + 1048832);            // 512 KB
  unsigned short* h_buf = (unsigned short*)(ws + 1573120);   // 16.8 MB
  unsigned short* xh    = (unsigned short*)(ws + 18350336);  // 4.2 MB
  unsigned* qk1         = (unsigned*)(ws + 22544640);        // 16.8 MB (nibbles along K, interleaved)
  unsigned* qk2         = (unsigned*)(ws + 39321856);        // 16.8 MB
  unsigned short* p_buf = (unsigned short*)(ws + 56099072);  // 33.6 MB
  float* partial        = (float*)(ws + 56099072);           // 8 MB (aliases p_buf; dead before gemm2)
  int2* tiles           = (int2*)(ws + 89653504);            // 2.6 KB dense tile list
  int* tile_cnt         = (int*)(ws + 89656064);             // 4 B
  int* done_ctr         = (int*)(ws + 89656068);             // 4 B

  // 5 dispatches total (was 10 incl. memset): prep, topk(+tilebuild), gemm1, gemm2, reduce
  prep_kernel<<<1536, 256, 0, stream>>>(x, gate_w, xh, partial, qw1, qk1, qw2, qk2,
                                        counts, done_ctr);
  topk_kernel<<<T_TOK / 4, 256, 0, stream>>>(partial, counts, tok_list, hslot_list, cw_list,
                                             tiles, tile_cnt, done_ctr);

  mfma_gemm1<<<dim3(IMED / 64, MAXTILES), 256, 0, stream>>>(
      xh, qk1, qz1, sc1, counts, tiles, tile_cnt, tok_list, hslot_list, cw_list, h_buf);
  mfma_gemm2<<<dim3(HID / 64, MAXTILES), 256, 0, stream>>>(
      h_buf, qk2, qz2, sc2, counts, tiles, tile_cnt, hslot_list, p_buf);
  reduce_kernel<<<(T_TOK * HID / 8) / 256, 256, 0, stream>>>(p_buf, out);
}

// Round 12
// 243.531 us; speedup vs baseline: 1.1996x; 1.1996x over previous
//
#include <hip/hip_runtime.h>
#include <hip/hip_bf16.h>

#define T_TOK 2048
#define HID   1024
#define EXP   64
#define TOPK  8
#define IMED  512
#define N1 (EXP * IMED)   // 32768
#define C1 (N1 / 8)       // 4096
#define N2 (EXP * HID)    // 65536
#define C2 (N2 / 8)       // 8192
#define MAXTILES 320      // >= sum ceil(n_e/64) worst case (256 + 64)

typedef _Float16 h16x2 __attribute__((ext_vector_type(2)));
typedef _Float16 h16x8 __attribute__((ext_vector_type(8)));
typedef float f32x4 __attribute__((ext_vector_type(4)));
typedef unsigned short ushortx4 __attribute__((ext_vector_type(4)));
typedef unsigned short ushortx8 __attribute__((ext_vector_type(8)));

__constant__ int kShifts[8] = {0, 16, 4, 20, 8, 24, 12, 28};

__device__ __forceinline__ void async16(const void* g, void* l) {
  __builtin_amdgcn_global_load_lds((const __attribute__((address_space(1))) void*)g,
                                   (__attribute__((address_space(3))) void*)l, 16, 0, 0);
}

__device__ __forceinline__ unsigned short f2h(float f) {
  return __builtin_bit_cast(unsigned short, (_Float16)f);
}
__device__ __forceinline__ float h2f(unsigned short b) {
  return (float)__builtin_bit_cast(_Float16, b);
}

// magic fp16 dequant: nibble|0x6400 = fp16(1024+q); (1024+q)-(1024+z) exact; *s.
__device__ __forceinline__ h16x8 unpack8h(unsigned q, h16x2 sh2, h16x2 zh2) {
  union { unsigned u[4]; h16x8 v; } out;
#pragma unroll
  for (int j = 0; j < 4; ++j) {
    const unsigned m = ((q >> (4 * j)) & 0x000F000Fu) | 0x64006400u;
    h16x2 d = __builtin_bit_cast(h16x2, m) - zh2;
    d = d * sh2;
    out.u[j] = __builtin_bit_cast(unsigned, d);
  }
  return out.v;
}

// ---------------- Repack body (verified R6/R9): AWQ nibbles -> qk[nblk][t][fq][fr][2] ----------------
__device__ __forceinline__ void repack_body(const int* __restrict__ qw,
                                            unsigned* __restrict__ qk, int K, int C,
                                            int gx, int pp, int tid) {
  const int t = pp >> 2, fq = pp & 3;
  const int c2 = gx * 512 + tid * 2;  // even qw dword-col
  const int nblk = c2 >> 1;
  unsigned o0[16], o1[16];
#pragma unroll
  for (int i = 0; i < 16; ++i) { o0[i] = 0u; o1[i] = 0u; }
  const int k0a = t * 64 + fq * 8;
  const int k0b = t * 64 + (fq + 4) * 8;
#pragma unroll
  for (int r = 0; r < 8; ++r) {
    const int2 va = *reinterpret_cast<const int2*>(qw + (size_t)(k0a + r) * C + c2);
    const int2 vb = *reinterpret_cast<const int2*>(qw + (size_t)(k0b + r) * C + c2);
    const int outsh = (r & 1) * 16 + (r >> 1) * 4;
    const unsigned qa[2] = {(unsigned)va.x, (unsigned)va.y};
    const unsigned qb[2] = {(unsigned)vb.x, (unsigned)vb.y};
#pragma unroll
    for (int ci = 0; ci < 2; ++ci) {
#pragma unroll
      for (int j = 0; j < 8; ++j) {
        const int sh = kShifts[j];
        o0[ci * 8 + j] |= ((qa[ci] >> sh) & 0xFu) << outsh;
        o1[ci * 8 + j] |= ((qb[ci] >> sh) & 0xFu) << outsh;
      }
    }
  }
  unsigned* dst = qk + (size_t)nblk * 2 * K + t * 128 + fq * 32;
#pragma unroll
  for (int idx = 0; idx < 16; ++idx)
    *reinterpret_cast<uint2*>(dst + idx * 2) = make_uint2(o0[idx], o1[idx]);
}

// ---------------- Prep: one launch = {cast+logits f32 16-split (R9 verified)} U repack1 U repack2 ----------------
// bid 0..511: logits tile (32 t-tiles x 16 k-splits of 64), writes xh during staging.
// bid 512..1023: repack1.  bid 1024..1535: repack2 (block 1535 also zeros counts).
__global__ __launch_bounds__(256) void prep_kernel(
    const float* __restrict__ x, const float* __restrict__ gate_w,
    unsigned short* __restrict__ xh, float* __restrict__ partial,
    const int* __restrict__ qw1, unsigned* __restrict__ qk1,
    const int* __restrict__ qw2, unsigned* __restrict__ qk2,
    int* __restrict__ counts) {
  const int bid = blockIdx.x;
  const int tid = threadIdx.x;
  if (bid == 1535 && tid < 64) counts[tid] = 0;
  if (bid < 512) {
    __shared__ float xs[64][64];
    __shared__ float gs[64][64];
    const int t0 = (bid & 31) * 64;
    const int ks = bid >> 5;   // 0..15
    const int k0 = ks * 64;
    const int lrow = tid >> 4;        // 0..15
    const int cblk = tid & 15;        // float4 block
#pragma unroll
    for (int r = 0; r < 4; ++r) {
      const int row = r * 16 + lrow;
      const int sc = (cblk ^ ((row >> 2) & 15)) * 4;  // XOR swizzle (16 f4-blocks/row)
      float4 xv = *reinterpret_cast<const float4*>(x + (size_t)(t0 + row) * HID + k0 + cblk * 4);
      float4 gv = *reinterpret_cast<const float4*>(gate_w + (size_t)row * HID + k0 + cblk * 4);
      *reinterpret_cast<float4*>(&xs[row][sc]) = xv;
      *reinterpret_cast<float4*>(&gs[row][sc]) = gv;
      ushortx4 o;
      o[0] = f2h(xv.x); o[1] = f2h(xv.y); o[2] = f2h(xv.z); o[3] = f2h(xv.w);
      *reinterpret_cast<ushortx4*>(xh + (size_t)(t0 + row) * HID + k0 + cblk * 4) = o;
    }
    __syncthreads();
    const int tg = (tid >> 4) * 4, eg = (tid & 15) * 4;
    const int xsw = tid >> 4, gsw = tid & 15;
    float acc[4][4] = {{0.f, 0.f, 0.f, 0.f}};
#pragma unroll 4
    for (int c = 0; c < 16; ++c) {
      float4 a[4], b[4];
#pragma unroll
      for (int i = 0; i < 4; ++i)
        a[i] = *reinterpret_cast<const float4*>(&xs[tg + i][(c ^ xsw) * 4]);
#pragma unroll
      for (int j = 0; j < 4; ++j)
        b[j] = *reinterpret_cast<const float4*>(&gs[eg + j][(c ^ gsw) * 4]);
#pragma unroll
      for (int i = 0; i < 4; ++i)
#pragma unroll
        for (int j = 0; j < 4; ++j) {
          acc[i][j] = fmaf(a[i].x, b[j].x, acc[i][j]);
          acc[i][j] = fmaf(a[i].y, b[j].y, acc[i][j]);
          acc[i][j] = fmaf(a[i].z, b[j].z, acc[i][j]);
          acc[i][j] = fmaf(a[i].w, b[j].w, acc[i][j]);
        }
    }
    float* dst = partial + ((size_t)ks * T_TOK + t0) * EXP;
#pragma unroll
    for (int i = 0; i < 4; ++i)
      *reinterpret_cast<float4*>(dst + (tg + i) * EXP + eg) =
          make_float4(acc[i][0], acc[i][1], acc[i][2], acc[i][3]);
  } else if (bid < 1024) {
    const int id = bid - 512;
    repack_body(qw1, qk1, HID, C1, id & 7, id >> 3, tid);
  } else {
    const int id = bid - 1024;
    repack_body(qw2, qk2, IMED, C2, id & 15, id >> 4, tid);
  }
}

// ---------------- Top-k: one wave per token; folds the 16-way k-split sum (R10 body, NO fence) ----------------
__global__ __launch_bounds__(256) void topk_kernel(
    const float* __restrict__ partial, int* __restrict__ counts,
    int* __restrict__ tok_list, int* __restrict__ hslot_list,
    float* __restrict__ cw_list) {
  const int wave = threadIdx.x >> 6, lane = threadIdx.x & 63;
  const int t = blockIdx.x * 4 + wave;
  float lg = 0.f;
#pragma unroll
  for (int s = 0; s < 16; ++s)
    lg += partial[((size_t)s * T_TOK + t) * EXP + lane];

  float m = lg;
  for (int off = 32; off; off >>= 1) m = fmaxf(m, __shfl_xor(m, off));
  float pe = expf(lg - m);
  float s = pe;
  for (int off = 32; off; off >>= 1) s += __shfl_xor(s, off);
  float prob = pe / s;

  float pcur = prob;
  float myv = 0.f;
  int myi = -1;
  float tsum = 0.f;
  for (int k = 0; k < TOPK; ++k) {
    float vv = pcur;
    int idx = lane;
    for (int off = 32; off; off >>= 1) {
      float ov = __shfl_xor(vv, off);
      int oi = __shfl_xor(idx, off);
      if (ov > vv || (ov == vv && oi < idx)) { vv = ov; idx = oi; }
    }
    tsum += vv;
    if (lane == k) { myv = vv; myi = idx; }
    if (lane == idx) pcur = -1.f;
  }

  if (lane < TOPK) {
    const float cw = myv / tsum;
    const int ex = myi;
    const int slot = atomicAdd(&counts[ex], 1);
    tok_list[ex * T_TOK + slot] = t;
    hslot_list[ex * T_TOK + slot] = t * TOPK + lane;
    cw_list[ex * T_TOK + slot] = cw;
  }
}

// ---------------- In-kernel tile lookup: wave-0 prefix scan over counts -> (e, t0, n_e) ----------------
// counts written by topk across a kernel boundary (coherent, R10-verified pattern).
// sh[0..2] = e,t0,n_e (written by exactly one lane); sh[3] = total tiles (lane 63).
#define TILE_LOOKUP(counts_ptr)                                            \
  __shared__ int sh_tl[4];                                                 \
  {                                                                        \
    if (threadIdx.x < 64) {                                                \
      const int n_ = (counts_ptr)[threadIdx.x];                            \
      const int nt_ = (n_ + 63) >> 6;                                      \
      int off_ = nt_;                                                      \
      for (int d_ = 1; d_ < 64; d_ <<= 1) {                                \
        const int v_ = __shfl_up(off_, d_);                                \
        if ((int)threadIdx.x >= d_) off_ += v_;                            \
      }                                                                    \
      const int excl_ = off_ - nt_;                                        \
      const int y_ = blockIdx.y;                                           \
      if (y_ >= excl_ && y_ < excl_ + nt_) {                               \
        sh_tl[0] = threadIdx.x; sh_tl[1] = (y_ - excl_) * 64; sh_tl[2] = n_; \
      }                                                                    \
      if (threadIdx.x == 63) sh_tl[3] = excl_ + nt_;                       \
    }                                                                      \
    __syncthreads();                                                       \
  }                                                                        \
  if ((int)blockIdx.y >= sh_tl[3]) return;                                 \
  const int e = sh_tl[0], t0 = sh_tl[1], n_e = sh_tl[2];

// ---------------- MFMA GEMM1: M64xN64, waves 1x4, BK=64, fp16 magic dequant (R10 body, verified) ----------------
__global__ __launch_bounds__(256) void mfma_gemm1(
    const unsigned short* __restrict__ xh, const unsigned* __restrict__ qk1,
    const int* __restrict__ qz1, const float* __restrict__ sc1,
    const int* __restrict__ counts, const int* __restrict__ tok_list,
    const int* __restrict__ hslot_list, const float* __restrict__ cw_list,
    unsigned short* __restrict__ h_buf) {
  TILE_LOOKUP(counts)
  const int ntile = blockIdx.x;  // 0..7
  const int tid = threadIdx.x;
  const int wave = tid >> 6, lane = tid & 63;
  const int fr = lane & 15, fq = lane >> 4;

  __shared__ unsigned short As[2][64 * 64];  // 2 x 8KB, XOR-swizzled source (verified R4)

  const int arow = tid >> 3;                            // 0..31
  const int acb = ((tid & 7) ^ ((tid >> 3) & 7)) * 16;  // pre-swizzled byte col
  const int ta0 = tok_list[e * T_TOK + min(t0 + arow, n_e - 1)];
  const int ta1 = tok_list[e * T_TOK + min(t0 + 32 + arow, n_e - 1)];
  const char* ga0 = (const char*)(xh + (size_t)ta0 * HID) + acb;
  const char* ga1 = (const char*)(xh + (size_t)ta1 * HID) + acb;

  auto stage = [&](int b) {
    char* l = (char*)&As[b][0] + wave * 1024;  // + HW lane*16
    async16(ga0, l);
    async16(ga1, l + 4096);
    ga0 += 128; ga1 += 128;
  };

  // B: qk1[nblk][t][fq][fr][2]; wave owns 16 cols, lane col = nbase + fr
  const int nbase = e * IMED + ntile * 64 + wave * 16;
  const unsigned* bp = qk1 + (size_t)(nbase >> 4) * (2 * HID) + fq * 32 + fr * 2;
  const int col = nbase + fr;
  const int shz = ((fr >> 1) & 3) * 4 + (fr & 1) * 16;  // kShifts[fr&7]

  f32x4 acc[4];
#pragma unroll
  for (int i = 0; i < 4; ++i) acc[i] = (f32x4){0.f, 0.f, 0.f, 0.f};

  stage(0);
  uint2 qcur = *reinterpret_cast<const uint2*>(bp);
  float s_cur = sc1[col];
  unsigned zd_cur = (unsigned)qz1[col >> 3];
  int p = 0;
#pragma unroll 1
  for (int g = 0; g < HID / 128; ++g) {
    const unsigned shb = (unsigned)f2h(s_cur);
    const h16x2 sh2 = __builtin_bit_cast(h16x2, shb | (shb << 16));
    const unsigned zb = 0x6400u | ((zd_cur >> shz) & 15u);
    const h16x2 zh2 = __builtin_bit_cast(h16x2, zb | (zb << 16));
    float s_nxt = 0.f; unsigned zd_nxt = 0u;
#pragma unroll
    for (int hh = 0; hh < 2; ++hh) {
      const int t = g * 2 + hh;
      __syncthreads();  // As[p] ready
      if (t + 1 < HID / 64) stage(p ^ 1);
      uint2 qnext = make_uint2(0u, 0u);
      if (t + 1 < HID / 64) qnext = *reinterpret_cast<const uint2*>(bp + (t + 1) * 128);
      if (hh == 1 && g + 1 < HID / 128) {
        s_nxt = sc1[(size_t)(g + 1) * N1 + col];
        zd_nxt = (unsigned)qz1[(size_t)(g + 1) * C1 + (col >> 3)];
      }
      const h16x8 b0 = unpack8h(qcur.x, sh2, zh2);
      const h16x8 b1 = unpack8h(qcur.y, sh2, zh2);
#pragma unroll
      for (int kk = 0; kk < 2; ++kk) {
        const h16x8 bb = kk ? b1 : b0;
#pragma unroll
        for (int i = 0; i < 4; ++i) {
          const int row = i * 16 + fr;
          const h16x8 a = *reinterpret_cast<const h16x8*>(
              &As[p][row * 64 + (((kk * 4 + fq) ^ (fr & 7)) * 8)]);
          acc[i] = __builtin_amdgcn_mfma_f32_16x16x32_f16(a, bb, acc[i], 0, 0, 0);
        }
      }
      qcur = qnext; p ^= 1;
    }
    s_cur = s_nxt; zd_cur = zd_nxt;
  }

  // epilogue: C/D map col = lane&15, row = (lane>>4)*4 + reg
#pragma unroll
  for (int i = 0; i < 4; ++i) {
#pragma unroll
    for (int r = 0; r < 4; ++r) {
      const int grow = t0 + i * 16 + fq * 4 + r;
      if (grow < n_e) {
        const float cw = cw_list[e * T_TOK + grow];
        const int hs = hslot_list[e * T_TOK + grow];
        const float v = acc[i][r];
        h_buf[(size_t)hs * IMED + ntile * 64 + wave * 16 + fr] =
            f2h((v / (1.f + expf(-v))) * cw);
      }
    }
  }
}

// ---------------- MFMA GEMM2: M64xN64, waves 1x4, BK=64, fp16 magic dequant (R10 body, verified) ----------------
__global__ __launch_bounds__(256) void mfma_gemm2(
    const unsigned short* __restrict__ h_buf, const unsigned* __restrict__ qk2,
    const int* __restrict__ qz2, const float* __restrict__ sc2,
    const int* __restrict__ counts, const int* __restrict__ hslot_list,
    unsigned short* __restrict__ p_buf) {
  TILE_LOOKUP(counts)
  const int ntile = blockIdx.x;  // 0..15
  const int tid = threadIdx.x;
  const int wave = tid >> 6, lane = tid & 63;
  const int fr = lane & 15, fq = lane >> 4;

  __shared__ unsigned short As[2][64 * 64];

  const int arow = tid >> 3;
  const int acb = ((tid & 7) ^ ((tid >> 3) & 7)) * 16;
  const int ha0 = hslot_list[e * T_TOK + min(t0 + arow, n_e - 1)];
  const int ha1 = hslot_list[e * T_TOK + min(t0 + 32 + arow, n_e - 1)];
  const char* ga0 = (const char*)(h_buf + (size_t)ha0 * IMED) + acb;
  const char* ga1 = (const char*)(h_buf + (size_t)ha1 * IMED) + acb;

  auto stage = [&](int b) {
    char* l = (char*)&As[b][0] + wave * 1024;
    async16(ga0, l);
    async16(ga1, l + 4096);
    ga0 += 128; ga1 += 128;
  };

  const int nbase = e * HID + ntile * 64 + wave * 16;
  const unsigned* bp = qk2 + (size_t)(nbase >> 4) * (2 * IMED) + fq * 32 + fr * 2;
  const int col = nbase + fr;
  const int shz = ((fr >> 1) & 3) * 4 + (fr & 1) * 16;

  f32x4 acc[4];
#pragma unroll
  for (int i = 0; i < 4; ++i) acc[i] = (f32x4){0.f, 0.f, 0.f, 0.f};

  stage(0);
  uint2 qcur = *reinterpret_cast<const uint2*>(bp);
  float s_cur = sc2[col];
  unsigned zd_cur = (unsigned)qz2[col >> 3];
  int p = 0;
#pragma unroll 1
  for (int g = 0; g < IMED / 128; ++g) {
    const unsigned shb = (unsigned)f2h(s_cur);
    const h16x2 sh2 = __builtin_bit_cast(h16x2, shb | (shb << 16));
    const unsigned zb = 0x6400u | ((zd_cur >> shz) & 15u);
    const h16x2 zh2 = __builtin_bit_cast(h16x2, zb | (zb << 16));
    float s_nxt = 0.f; unsigned zd_nxt = 0u;
#pragma unroll
    for (int hh = 0; hh < 2; ++hh) {
      const int t = g * 2 + hh;
      __syncthreads();
      if (t + 1 < IMED / 64) stage(p ^ 1);
      uint2 qnext = make_uint2(0u, 0u);
      if (t + 1 < IMED / 64) qnext = *reinterpret_cast<const uint2*>(bp + (t + 1) * 128);
      if (hh == 1 && g + 1 < IMED / 128) {
        s_nxt = sc2[(size_t)(g + 1) * N2 + col];
        zd_nxt = (unsigned)qz2[(size_t)(g + 1) * C2 + (col >> 3)];
      }
      const h16x8 b0 = unpack8h(qcur.x, sh2, zh2);
      const h16x8 b1 = unpack8h(qcur.y, sh2, zh2);
#pragma unroll
      for (int kk = 0; kk < 2; ++kk) {
        const h16x8 bb = kk ? b1 : b0;
#pragma unroll
        for (int i = 0; i < 4; ++i) {
          const int row = i * 16 + fr;
          const h16x8 a = *reinterpret_cast<const h16x8*>(
              &As[p][row * 64 + (((kk * 4 + fq) ^ (fr & 7)) * 8)]);
          acc[i] = __builtin_amdgcn_mfma_f32_16x16x32_f16(a, bb, acc[i], 0, 0, 0);
        }
      }
      qcur = qnext; p ^= 1;
    }
    s_cur = s_nxt; zd_cur = zd_nxt;
  }

  // epilogue: plain fp16 partial stores; every (hslot, col) written once
#pragma unroll
  for (int i = 0; i < 4; ++i) {
#pragma unroll
    for (int r = 0; r < 4; ++r) {
      const int grow = t0 + i * 16 + fq * 4 + r;
      if (grow < n_e) {
        const int hs = hslot_list[e * T_TOK + grow];
        p_buf[(size_t)hs * HID + ntile * 64 + wave * 16 + fr] = f2h(acc[i][r]);
      }
    }
  }
}

// ---------------- Reduce 8 partials per token -> out (fp32, verified R8) ----------------
__global__ __launch_bounds__(256) void reduce_kernel(const unsigned short* __restrict__ p_buf,
                                                     float* __restrict__ out) {
  const int idx = blockIdx.x * 256 + threadIdx.x;
  const int t = idx >> 7;
  const int c0 = (idx & 127) * 8;
  float s[8] = {0.f, 0.f, 0.f, 0.f, 0.f, 0.f, 0.f, 0.f};
#pragma unroll
  for (int k = 0; k < TOPK; ++k) {
    ushortx8 v = *reinterpret_cast<const ushortx8*>(p_buf + ((size_t)t * TOPK + k) * HID + c0);
#pragma unroll
    for (int j = 0; j < 8; ++j) s[j] += h2f(v[j]);
  }
  float* dst = out + (size_t)t * HID + c0;
  *reinterpret_cast<float4*>(dst) = make_float4(s[0], s[1], s[2], s[3]);
  *reinterpret_cast<float4*>(dst + 4) = make_float4(s[4], s[5], s[6], s[7]);
}

extern "C" void kernel_launch(void* const* d_in, const int* in_sizes, int n_in,
                              void* d_out, int out_size, void* d_ws, size_t ws_size,
                              hipStream_t stream) {
  const float* x      = (const float*)d_in[0];
  const float* gate_w = (const float*)d_in[1];
  const int*   qw1    = (const int*)d_in[2];
  const int*   qz1    = (const int*)d_in[3];
  const float* sc1    = (const float*)d_in[4];
  const int*   qw2    = (const int*)d_in[5];
  const int*   qz2    = (const int*)d_in[6];
  const float* sc2    = (const float*)d_in[7];
  float* out = (float*)d_out;

  // workspace layout
  char* ws = (char*)d_ws;
  int* counts           = (int*)(ws);                        // 256 B
  int* tok_list         = (int*)(ws + 256);                  // 512 KB
  int* hslot_list       = (int*)(ws + 524544);               // 512 KB
  float* cw_list        = (float*)(ws + 1048832);            // 512 KB
  unsigned short* h_buf = (unsigned short*)(ws + 1573120);   // 16.8 MB
  unsigned short* xh    = (unsigned short*)(ws + 18350336);  // 4.2 MB
  unsigned* qk1         = (unsigned*)(ws + 22544640);        // 16.8 MB (nibbles along K, interleaved)
  unsigned* qk2         = (unsigned*)(ws + 39321856);        // 16.8 MB
  unsigned short* p_buf = (unsigned short*)(ws + 56099072);  // 33.6 MB
  float* partial        = (float*)(ws + 56099072);           // 8 MB (aliases p_buf; dead before gemm2)

  // 5 dispatches: prep, topk, gemm1, gemm2, reduce (no memset, no fences)
  prep_kernel<<<1536, 256, 0, stream>>>(x, gate_w, xh, partial, qw1, qk1, qw2, qk2, counts);
  topk_kernel<<<T_TOK / 4, 256, 0, stream>>>(partial, counts, tok_list, hslot_list, cw_list);

  mfma_gemm1<<<dim3(IMED / 64, MAXTILES), 256, 0, stream>>>(
      xh, qk1, qz1, sc1, counts, tok_list, hslot_list, cw_list, h_buf);
  mfma_gemm2<<<dim3(HID / 64, MAXTILES), 256, 0, stream>>>(
      h_buf, qk2, qz2, sc2, counts, hslot_list, p_buf);
  reduce_kernel<<<(T_TOK * HID / 8) / 256, 256, 0, stream>>>(p_buf, out);
}